// Round 4
// baseline (706.917 us; speedup 1.0000x reference)
//
#include <hip/hip_runtime.h>
#include <math.h>

#define B_ 32
#define L_ 2049
#define E_ 1024
#define H_ 16
#define NT_ 16
#define STILE 128

// workspace layout (float offsets). UP stored as bf16 (2 ushort per float slot).
#define OFF_Q     0
#define OFF_T     (OFF_Q + B_*E_)
#define OFF_QBK   (OFF_T + B_*H_*E_)
#define OFF_M     (OFF_QBK + B_*H_)
#define OFF_L     (OFF_M + B_*NT_*H_)
#define OFF_U     (OFF_L + B_*NT_*H_)
#define OFF_ATTN  (OFF_U + B_*H_*E_)
#define OFF_Y     (OFF_ATTN + B_*E_)
#define OFF_UP    (OFF_Y + B_*E_)          // bf16: B*NT*H*E ushorts

__device__ __forceinline__ unsigned bf16pair(float a, float b) {
    unsigned ua = __float_as_uint(a), ub = __float_as_uint(b);
    ua = (ua + 0x7FFFu + ((ua >> 16) & 1u)) >> 16;
    ub = (ub + 0x7FFFu + ((ub >> 16) & 1u)) >> 16;
    return ua | (ub << 16);
}

// ---------------------------------------------------------------- generic 32xE GEMM (round-2 proven)
__global__ __launch_bounds__(256) void k_gemm32(const float* __restrict__ A, long long As, int mode,
                                                const float* __restrict__ W,
                                                const float* __restrict__ bias,
                                                const float* __restrict__ resid, long long Rs,
                                                float* __restrict__ C) {
    __shared__ float wls[2 * 1056];
    const int j0 = blockIdx.x * 2, tid = threadIdx.x;
    #pragma unroll
    for (int k = 0; k < 2; ++k) {
        int idx4 = k * 256 + tid;
        int row = idx4 >> 8, c4 = idx4 & 255;
        float4 v = *(const float4*)(W + (size_t)(j0 + row) * E_ + 4 * c4);
        *(float4*)&wls[row * 1056 + 4 * c4 + ((c4 >> 5) << 2)] = v;
    }
    __syncthreads();
    const int bb = tid >> 3, kseg = tid & 7;
    const long long kbase = (mode == 1) ? (long long)(j0 >> 6) * E_ : 0;
    const float* arow = A + (size_t)bb * As + kbase + kseg * 128;
    float a0 = 0.f, a1 = 0.f;
    #pragma unroll 4
    for (int i = 0; i < 32; ++i) {
        float4 av = *(const float4*)(arow + 4 * i);
        const float* wb = &wls[kseg * 132 + 4 * i];
        float4 w0 = *(const float4*)(wb);
        float4 w1 = *(const float4*)(wb + 1056);
        a0 += av.x * w0.x + av.y * w0.y + av.z * w0.z + av.w * w0.w;
        a1 += av.x * w1.x + av.y * w1.y + av.z * w1.z + av.w * w1.w;
    }
    #pragma unroll
    for (int off = 4; off; off >>= 1) {
        a0 += __shfl_down(a0, off, 8);
        a1 += __shfl_down(a1, off, 8);
    }
    if (kseg == 0) {
        float r0 = a0 + bias[j0], r1 = a1 + bias[j0 + 1];
        if (resid) {
            r0 += resid[(size_t)bb * Rs + j0];
            r1 += resid[(size_t)bb * Rs + j0 + 1];
        }
        C[(size_t)bb * E_ + j0] = r0;
        C[(size_t)bb * E_ + j0 + 1] = r1;
    }
}

// ---------------------------------------------------------------- t = 0.125*q_h@Wk_h ; qbk (round-2 proven)
__global__ __launch_bounds__(256) void k_tproj(const float* __restrict__ Wk,
                                               const float* __restrict__ bk,
                                               float* __restrict__ ws) {
    __shared__ float qs[64 * 33];
    __shared__ float wls[64 * 68];
    const int h = blockIdx.x, e0 = blockIdx.y * 64, tid = threadIdx.x;
    const float* q = ws + OFF_Q;
    #pragma unroll
    for (int k = 0; k < 8; ++k) {
        int idx = k * 256 + tid;
        int b = idx >> 6, d = idx & 63;
        qs[d * 33 + b] = q[(size_t)b * E_ + 64 * h + d];
    }
    #pragma unroll
    for (int k = 0; k < 4; ++k) {
        int idx4 = k * 256 + tid;
        int d = idx4 >> 4, c4 = idx4 & 15;
        float4 v = *(const float4*)(Wk + (size_t)(64 * h + d) * E_ + e0 + 4 * c4);
        *(float4*)&wls[d * 68 + 4 * c4] = v;
    }
    __syncthreads();
    const int el = tid & 63, bq8 = tid >> 6;
    float acc[8];
    #pragma unroll
    for (int i = 0; i < 8; ++i) acc[i] = 0.f;
    for (int d = 0; d < 64; ++d) {
        float wv = wls[d * 68 + el];
        #pragma unroll
        for (int i = 0; i < 8; ++i) acc[i] += qs[d * 33 + (bq8 * 8 + i)] * wv;
    }
    float* t = ws + OFF_T;
    #pragma unroll
    for (int i = 0; i < 8; ++i)
        t[((size_t)(bq8 * 8 + i) * H_ + h) * E_ + e0 + el] = acc[i] * 0.125f;
    if (e0 == 0 && tid < 32) {
        float s = 0.f;
        for (int d = 0; d < 64; ++d) s += qs[d * 33 + tid] * bk[64 * h + d];
        ws[OFF_QBK + tid * H_ + h] = s * 0.125f;
    }
}

// ---------------------------------------------------------------- fused scores/softmax/u_part
// 256 thr (4 waves), STILE=128, grid 512 = 2 blocks/CU (grid-limited residency).
// __launch_bounds__(256, 2): min 2 waves/EU -> VGPR cap 256, prevents the round-3
// acc2 spill (VGPR=84 forced ~1.07 GB scratch write-back; need ~106 live VGPRs).
__global__ __launch_bounds__(256, 2) void k_attn_core(const float* __restrict__ x,
                                                      float* __restrict__ ws) {
    const int tile = blockIdx.x, b = blockIdx.y, tid = threadIdx.x;
    const float* tmat = ws + OFF_T + (size_t)b * H_ * E_;
    const float* xb = x + (size_t)(b * L_ + 1 + tile * STILE) * E_;

    __shared__ float xs[9216];   // 2 bufs of 128x36; reduce planes 4x2176 reuse this
    __shared__ float ts[1152];   // 2 bufs of 16x36
    __shared__ float wl[128 * 20];
    __shared__ float red[256];
    __shared__ float msh[16];

    const int lane = tid & 63, w = tid >> 6;
    const int sl = lane & 31, eh = lane >> 5;
    const int qd = 2 * w + eh;  // e-quad 0..7 within 32-e chunk

    // ================= phase 1: scores =================
    float acc[16][4];
    #pragma unroll
    for (int h = 0; h < 16; ++h)
        #pragma unroll
        for (int si = 0; si < 4; ++si) acc[h][si] = 0.f;

    float4 xr[4];
    float tr[2];
    {
        #pragma unroll
        for (int k = 0; k < 4; ++k) {
            int i4 = k * 256 + tid, s = i4 >> 3, e4 = i4 & 7;
            xr[k] = *(const float4*)(xb + (size_t)s * E_ + 4 * e4);
        }
        #pragma unroll
        for (int k = 0; k < 2; ++k) {
            int idx = k * 256 + tid, hh = idx >> 5, e = idx & 31;
            tr[k] = tmat[hh * E_ + e];
        }
        #pragma unroll
        for (int k = 0; k < 4; ++k) {
            int i4 = k * 256 + tid, s = i4 >> 3, e4 = i4 & 7;
            *(float4*)&xs[s * 36 + 4 * e4] = xr[k];
        }
        #pragma unroll
        for (int k = 0; k < 2; ++k) {
            int idx = k * 256 + tid, hh = idx >> 5, e = idx & 31;
            ts[hh * 36 + e] = tr[k];
        }
    }
    for (int c = 0; c < 32; ++c) {
        __syncthreads();
        if (c + 1 < 32) {
            int ec = (c + 1) * 32;
            #pragma unroll
            for (int k = 0; k < 4; ++k) {
                int i4 = k * 256 + tid, s = i4 >> 3, e4 = i4 & 7;
                xr[k] = *(const float4*)(xb + (size_t)s * E_ + ec + 4 * e4);
            }
            #pragma unroll
            for (int k = 0; k < 2; ++k) {
                int idx = k * 256 + tid, hh = idx >> 5, e = idx & 31;
                tr[k] = tmat[hh * E_ + ec + e];
            }
        }
        const int bx = (c & 1) * 4608, bt = (c & 1) * 576;
        float4 xv[4];
        #pragma unroll
        for (int si = 0; si < 4; ++si)
            xv[si] = *(const float4*)&xs[bx + (sl + 32 * si) * 36 + 4 * qd];
        #pragma unroll
        for (int h = 0; h < 16; ++h) {
            float4 tf = *(const float4*)&ts[bt + h * 36 + 4 * qd];
            #pragma unroll
            for (int si = 0; si < 4; ++si)
                acc[h][si] += tf.x * xv[si].x + tf.y * xv[si].y + tf.z * xv[si].z + tf.w * xv[si].w;
        }
        if (c + 1 < 32) {
            const int nx = ((c + 1) & 1) * 4608, nt = ((c + 1) & 1) * 576;
            #pragma unroll
            for (int k = 0; k < 4; ++k) {
                int i4 = k * 256 + tid, s = i4 >> 3, e4 = i4 & 7;
                *(float4*)&xs[nx + s * 36 + 4 * e4] = xr[k];
            }
            #pragma unroll
            for (int k = 0; k < 2; ++k) {
                int idx = k * 256 + tid, hh = idx >> 5, e = idx & 31;
                ts[nt + hh * 36 + e] = tr[k];
            }
        }
    }
    __syncthreads();  // all phase-1 reads done; xs becomes reduce planes

    // cross-eh butterfly: sum the two 4-e halves within the wave
    #pragma unroll
    for (int h = 0; h < 16; ++h)
        #pragma unroll
        for (int si = 0; si < 4; ++si)
            acc[h][si] += __shfl_xor(acc[h][si], 32, 64);
    {
        float* pl = xs + w * 2176;
        #pragma unroll
        for (int si = 0; si < 4; ++si) {
            int s = sl + 32 * si;
            #pragma unroll
            for (int hh = 0; hh < 8; ++hh)
                pl[s * 17 + 8 * eh + hh] = acc[8 * eh + hh][si];
        }
    }
    __syncthreads();
    {
        const float* qbk = ws + OFF_QBK + b * H_;
        #pragma unroll
        for (int i = 0; i < 8; ++i) {
            int o = tid * 8 + i, s = o >> 4, h = o & 15;
            float v = xs[s * 17 + h] + xs[2176 + s * 17 + h] +
                      xs[4352 + s * 17 + h] + xs[6528 + s * 17 + h] + qbk[h];
            wl[s * 20 + h] = v;
        }
    }
    __syncthreads();

    // ================= softmax partials =================
    const int sh = tid & 15, seg = tid >> 4;
    {
        float m = -1e30f;
        #pragma unroll
        for (int i = 0; i < 8; ++i) m = fmaxf(m, wl[(seg * 8 + i) * 20 + sh]);
        red[seg * 16 + sh] = m;
    }
    __syncthreads();
    if (tid < 16) {
        float mm = -1e30f;
        for (int g = 0; g < 16; ++g) mm = fmaxf(mm, red[g * 16 + tid]);
        msh[tid] = mm;
    }
    __syncthreads();
    {
        float M = msh[sh];
        float ps = 0.f;
        #pragma unroll
        for (int i = 0; i < 8; ++i) {
            int idx = (seg * 8 + i) * 20 + sh;
            float v = __expf(wl[idx] - M);
            wl[idx] = v;
            ps += v;
        }
        __syncthreads();
        red[seg * 16 + sh] = ps;
    }
    __syncthreads();
    if (tid < 16) {
        float ss = 0.f;
        for (int g = 0; g < 16; ++g) ss += red[g * 16 + tid];
        ws[OFF_M + (b * NT_ + tile) * H_ + tid] = msh[tid];
        ws[OFF_L + (b * NT_ + tile) * H_ + tid] = ss;
    }

    // ================= phase 2: direct-global x, no LDS staging =================
    float4 a2[16];
    #pragma unroll
    for (int h = 0; h < 16; ++h) a2[h] = make_float4(0.f, 0.f, 0.f, 0.f);
    const float* xb2 = xb + w * 256 + 4 * lane;  // wave w owns e-slice [256w,256w+256)
    for (int s = 0; s < STILE; s += 4) {
        float4 xv[4];
        #pragma unroll
        for (int u = 0; u < 4; ++u)
            xv[u] = *(const float4*)(xb2 + (size_t)(s + u) * E_);
        #pragma unroll
        for (int u = 0; u < 4; ++u) {
            const float* wp = &wl[(s + u) * 20];
            float4 w0 = *(const float4*)(wp);
            float4 w1 = *(const float4*)(wp + 4);
            float4 w2 = *(const float4*)(wp + 8);
            float4 w3 = *(const float4*)(wp + 12);
            a2[0].x += w0.x * xv[u].x; a2[0].y += w0.x * xv[u].y; a2[0].z += w0.x * xv[u].z; a2[0].w += w0.x * xv[u].w;
            a2[1].x += w0.y * xv[u].x; a2[1].y += w0.y * xv[u].y; a2[1].z += w0.y * xv[u].z; a2[1].w += w0.y * xv[u].w;
            a2[2].x += w0.z * xv[u].x; a2[2].y += w0.z * xv[u].y; a2[2].z += w0.z * xv[u].z; a2[2].w += w0.z * xv[u].w;
            a2[3].x += w0.w * xv[u].x; a2[3].y += w0.w * xv[u].y; a2[3].z += w0.w * xv[u].z; a2[3].w += w0.w * xv[u].w;
            a2[4].x += w1.x * xv[u].x; a2[4].y += w1.x * xv[u].y; a2[4].z += w1.x * xv[u].z; a2[4].w += w1.x * xv[u].w;
            a2[5].x += w1.y * xv[u].x; a2[5].y += w1.y * xv[u].y; a2[5].z += w1.y * xv[u].z; a2[5].w += w1.y * xv[u].w;
            a2[6].x += w1.z * xv[u].x; a2[6].y += w1.z * xv[u].y; a2[6].z += w1.z * xv[u].z; a2[6].w += w1.z * xv[u].w;
            a2[7].x += w1.w * xv[u].x; a2[7].y += w1.w * xv[u].y; a2[7].z += w1.w * xv[u].z; a2[7].w += w1.w * xv[u].w;
            a2[8].x += w2.x * xv[u].x; a2[8].y += w2.x * xv[u].y; a2[8].z += w2.x * xv[u].z; a2[8].w += w2.x * xv[u].w;
            a2[9].x += w2.y * xv[u].x; a2[9].y += w2.y * xv[u].y; a2[9].z += w2.y * xv[u].z; a2[9].w += w2.y * xv[u].w;
            a2[10].x += w2.z * xv[u].x; a2[10].y += w2.z * xv[u].y; a2[10].z += w2.z * xv[u].z; a2[10].w += w2.z * xv[u].w;
            a2[11].x += w2.w * xv[u].x; a2[11].y += w2.w * xv[u].y; a2[11].z += w2.w * xv[u].z; a2[11].w += w2.w * xv[u].w;
            a2[12].x += w3.x * xv[u].x; a2[12].y += w3.x * xv[u].y; a2[12].z += w3.x * xv[u].z; a2[12].w += w3.x * xv[u].w;
            a2[13].x += w3.y * xv[u].x; a2[13].y += w3.y * xv[u].y; a2[13].z += w3.y * xv[u].z; a2[13].w += w3.y * xv[u].w;
            a2[14].x += w3.z * xv[u].x; a2[14].y += w3.z * xv[u].y; a2[14].z += w3.z * xv[u].z; a2[14].w += w3.z * xv[u].w;
            a2[15].x += w3.w * xv[u].x; a2[15].y += w3.w * xv[u].y; a2[15].z += w3.w * xv[u].z; a2[15].w += w3.w * xv[u].w;
        }
    }
    {
        unsigned short* up = (unsigned short*)(ws + OFF_UP) +
                             (size_t)((b * NT_ + tile) * H_) * E_ + w * 256 + 4 * lane;
        #pragma unroll
        for (int h = 0; h < 16; ++h) {
            uint2 p;
            p.x = bf16pair(a2[h].x, a2[h].y);
            p.y = bf16pair(a2[h].z, a2[h].w);
            *(uint2*)(up + (size_t)h * E_) = p;
        }
    }
}

// ---------------------------------------------------------------- combine partial tiles (bf16 UP)
__global__ __launch_bounds__(256) void k_combine(float* __restrict__ ws) {
    const int b = blockIdx.x, h = blockIdx.y, tid = threadIdx.x;
    float m[NT_], l[NT_], f[NT_];
    float M = -1e30f;
    #pragma unroll
    for (int tg = 0; tg < NT_; ++tg) {
        m[tg] = ws[OFF_M + (b * NT_ + tg) * H_ + h];
        l[tg] = ws[OFF_L + (b * NT_ + tg) * H_ + h];
        M = fmaxf(M, m[tg]);
    }
    float Ls = 0.f;
    #pragma unroll
    for (int tg = 0; tg < NT_; ++tg) {
        f[tg] = __expf(m[tg] - M);
        Ls += f[tg] * l[tg];
    }
    const float inv = 1.f / Ls;
    const unsigned short* up = (const unsigned short*)(ws + OFF_UP);
    float4 a = make_float4(0.f, 0.f, 0.f, 0.f);
    #pragma unroll
    for (int tg = 0; tg < NT_; ++tg) {
        uint2 p = *(const uint2*)(up + (size_t)((b * NT_ + tg) * H_ + h) * E_ + 4 * tid);
        float v0 = __uint_as_float((p.x & 0xFFFFu) << 16);
        float v1 = __uint_as_float(p.x & 0xFFFF0000u);
        float v2 = __uint_as_float((p.y & 0xFFFFu) << 16);
        float v3 = __uint_as_float(p.y & 0xFFFF0000u);
        a.x += f[tg] * v0; a.y += f[tg] * v1; a.z += f[tg] * v2; a.w += f[tg] * v3;
    }
    a.x *= inv; a.y *= inv; a.z *= inv; a.w *= inv;
    *(float4*)(ws + OFF_U + (size_t)(b * H_ + h) * E_ + 4 * tid) = a;
}

// ---------------------------------------------------------------- LayerNorm -> out
__global__ __launch_bounds__(256) void k_ln(const float* __restrict__ ws,
                                            const float* __restrict__ g,
                                            const float* __restrict__ be,
                                            float* __restrict__ out) {
    const int b = blockIdx.x, tid = threadIdx.x;
    const float* y = ws + OFF_Y + (size_t)b * E_;
    float4 v = *(const float4*)(y + 4 * tid);
    float s = v.x + v.y + v.z + v.w;
    float s2 = v.x * v.x + v.y * v.y + v.z * v.z + v.w * v.w;
    for (int o = 32; o; o >>= 1) {
        s += __shfl_down(s, o, 64);
        s2 += __shfl_down(s2, o, 64);
    }
    __shared__ float rs[4], rs2[4];
    int ww = tid >> 6;
    if ((tid & 63) == 0) { rs[ww] = s; rs2[ww] = s2; }
    __syncthreads();
    float S = rs[0] + rs[1] + rs[2] + rs[3];
    float S2 = rs2[0] + rs2[1] + rs2[2] + rs2[3];
    float mean = S * (1.f / 1024.f);
    float var = S2 * (1.f / 1024.f) - mean * mean;
    float r = rsqrtf(var + 1e-5f);
    float4 gv = *(const float4*)(g + 4 * tid);
    float4 bb2 = *(const float4*)(be + 4 * tid);
    float4 o;
    o.x = (v.x - mean) * r * gv.x + bb2.x;
    o.y = (v.y - mean) * r * gv.y + bb2.y;
    o.z = (v.z - mean) * r * gv.z + bb2.z;
    o.w = (v.w - mean) * r * gv.w + bb2.w;
    *(float4*)(out + (size_t)b * E_ + 4 * tid) = o;
}

extern "C" void kernel_launch(void* const* d_in, const int* in_sizes, int n_in,
                              void* d_out, int out_size, void* d_ws, size_t ws_size,
                              hipStream_t stream) {
    const float* x  = (const float*)d_in[0];
    const float* Wq = (const float*)d_in[1];
    const float* bq = (const float*)d_in[2];
    const float* Wk = (const float*)d_in[3];
    const float* bk = (const float*)d_in[4];
    const float* Wv = (const float*)d_in[5];
    const float* bv = (const float*)d_in[6];
    const float* Wo = (const float*)d_in[7];
    const float* bo = (const float*)d_in[8];
    const float* g  = (const float*)d_in[9];
    const float* be = (const float*)d_in[10];
    float* ws = (float*)d_ws;
    float* out = (float*)d_out;

    k_gemm32<<<512, 256, 0, stream>>>(x, (long long)L_ * E_, 0, Wq, bq, nullptr, 0, ws + OFF_Q);
    k_tproj<<<dim3(16, 16), 256, 0, stream>>>(Wk, bk, ws);
    k_attn_core<<<dim3(NT_, B_), 256, 0, stream>>>(x, ws);
    k_combine<<<dim3(B_, H_), 256, 0, stream>>>(ws);
    k_gemm32<<<512, 256, 0, stream>>>(ws + OFF_U, (long long)H_ * E_, 1, Wv, bv, nullptr, 0, ws + OFF_ATTN);
    k_gemm32<<<512, 256, 0, stream>>>(ws + OFF_ATTN, (long long)E_, 0, Wo, bo, x, (long long)L_ * E_, ws + OFF_Y);
    k_ln<<<B_, 256, 0, stream>>>(ws, g, be, out);
}

// Round 5
// 703.090 us; speedup vs baseline: 1.0054x; 1.0054x over previous
//
#include <hip/hip_runtime.h>
#include <math.h>

#define B_ 32
#define L_ 2049
#define E_ 1024
#define H_ 16
#define NT_ 16
#define STILE 128

// workspace layout (float offsets). UP stored as bf16 (2 ushort per float slot).
#define OFF_Q     0
#define OFF_T     (OFF_Q + B_*E_)
#define OFF_QBK   (OFF_T + B_*H_*E_)
#define OFF_M     (OFF_QBK + B_*H_)
#define OFF_L     (OFF_M + B_*NT_*H_)
#define OFF_U     (OFF_L + B_*NT_*H_)
#define OFF_ATTN  (OFF_U + B_*H_*E_)
#define OFF_Y     (OFF_ATTN + B_*E_)
#define OFF_UP    (OFF_Y + B_*E_)          // bf16: B*NT*H*E ushorts

__device__ __forceinline__ unsigned bf16pair(float a, float b) {
    unsigned ua = __float_as_uint(a), ub = __float_as_uint(b);
    ua = (ua + 0x7FFFu + ((ua >> 16) & 1u)) >> 16;
    ub = (ub + 0x7FFFu + ((ub >> 16) & 1u)) >> 16;
    return ua | (ub << 16);
}

// ---------------------------------------------------------------- generic 32xE GEMM (round-2 proven)
__global__ __launch_bounds__(256) void k_gemm32(const float* __restrict__ A, long long As, int mode,
                                                const float* __restrict__ W,
                                                const float* __restrict__ bias,
                                                const float* __restrict__ resid, long long Rs,
                                                float* __restrict__ C) {
    __shared__ float wls[2 * 1056];
    const int j0 = blockIdx.x * 2, tid = threadIdx.x;
    #pragma unroll
    for (int k = 0; k < 2; ++k) {
        int idx4 = k * 256 + tid;
        int row = idx4 >> 8, c4 = idx4 & 255;
        float4 v = *(const float4*)(W + (size_t)(j0 + row) * E_ + 4 * c4);
        *(float4*)&wls[row * 1056 + 4 * c4 + ((c4 >> 5) << 2)] = v;
    }
    __syncthreads();
    const int bb = tid >> 3, kseg = tid & 7;
    const long long kbase = (mode == 1) ? (long long)(j0 >> 6) * E_ : 0;
    const float* arow = A + (size_t)bb * As + kbase + kseg * 128;
    float a0 = 0.f, a1 = 0.f;
    #pragma unroll 4
    for (int i = 0; i < 32; ++i) {
        float4 av = *(const float4*)(arow + 4 * i);
        const float* wb = &wls[kseg * 132 + 4 * i];
        float4 w0 = *(const float4*)(wb);
        float4 w1 = *(const float4*)(wb + 1056);
        a0 += av.x * w0.x + av.y * w0.y + av.z * w0.z + av.w * w0.w;
        a1 += av.x * w1.x + av.y * w1.y + av.z * w1.z + av.w * w1.w;
    }
    #pragma unroll
    for (int off = 4; off; off >>= 1) {
        a0 += __shfl_down(a0, off, 8);
        a1 += __shfl_down(a1, off, 8);
    }
    if (kseg == 0) {
        float r0 = a0 + bias[j0], r1 = a1 + bias[j0 + 1];
        if (resid) {
            r0 += resid[(size_t)bb * Rs + j0];
            r1 += resid[(size_t)bb * Rs + j0 + 1];
        }
        C[(size_t)bb * E_ + j0] = r0;
        C[(size_t)bb * E_ + j0 + 1] = r1;
    }
}

// ---------------------------------------------------------------- t = 0.125*q_h@Wk_h ; qbk (round-2 proven)
__global__ __launch_bounds__(256) void k_tproj(const float* __restrict__ Wk,
                                               const float* __restrict__ bk,
                                               float* __restrict__ ws) {
    __shared__ float qs[64 * 33];
    __shared__ float wls[64 * 68];
    const int h = blockIdx.x, e0 = blockIdx.y * 64, tid = threadIdx.x;
    const float* q = ws + OFF_Q;
    #pragma unroll
    for (int k = 0; k < 8; ++k) {
        int idx = k * 256 + tid;
        int b = idx >> 6, d = idx & 63;
        qs[d * 33 + b] = q[(size_t)b * E_ + 64 * h + d];
    }
    #pragma unroll
    for (int k = 0; k < 4; ++k) {
        int idx4 = k * 256 + tid;
        int d = idx4 >> 4, c4 = idx4 & 15;
        float4 v = *(const float4*)(Wk + (size_t)(64 * h + d) * E_ + e0 + 4 * c4);
        *(float4*)&wls[d * 68 + 4 * c4] = v;
    }
    __syncthreads();
    const int el = tid & 63, bq8 = tid >> 6;
    float acc[8];
    #pragma unroll
    for (int i = 0; i < 8; ++i) acc[i] = 0.f;
    for (int d = 0; d < 64; ++d) {
        float wv = wls[d * 68 + el];
        #pragma unroll
        for (int i = 0; i < 8; ++i) acc[i] += qs[d * 33 + (bq8 * 8 + i)] * wv;
    }
    float* t = ws + OFF_T;
    #pragma unroll
    for (int i = 0; i < 8; ++i)
        t[((size_t)(bq8 * 8 + i) * H_ + h) * E_ + e0 + el] = acc[i] * 0.125f;
    if (e0 == 0 && tid < 32) {
        float s = 0.f;
        for (int d = 0; d < 64; ++d) s += qs[d * 33 + tid] * bk[64 * h + d];
        ws[OFF_QBK + tid * H_ + h] = s * 0.125f;
    }
}

// ---------------------------------------------------------------- fused scores/softmax/u_part
// 256 thr (4 waves), STILE=128, grid 512 = 2 blocks/CU.
// ROUND-5 FIX: round 3/4 indexed acc[8*eh+hh] with eh=lane>>5 (runtime value) ->
// compiler demoted the whole acc[16][4] array to scratch (VGPR=84, 1.07 GB spill
// writes). Plane-store now selects between two CONSTANT-indexed values with a
// predicated move; only the LDS address is dynamic (which is fine).
__global__ __launch_bounds__(256, 2) void k_attn_core(const float* __restrict__ x,
                                                      float* __restrict__ ws) {
    const int tile = blockIdx.x, b = blockIdx.y, tid = threadIdx.x;
    const float* tmat = ws + OFF_T + (size_t)b * H_ * E_;
    const float* xb = x + (size_t)(b * L_ + 1 + tile * STILE) * E_;

    __shared__ float xs[9216];   // 2 bufs of 128x36; reduce planes 4x2176 reuse this
    __shared__ float ts[1152];   // 2 bufs of 16x36
    __shared__ float wl[128 * 20];
    __shared__ float red[256];
    __shared__ float msh[16];

    const int lane = tid & 63, w = tid >> 6;
    const int sl = lane & 31, eh = lane >> 5;
    const int qd = 2 * w + eh;  // e-quad 0..7 within 32-e chunk

    // ================= phase 1: scores =================
    float acc[16][4];
    #pragma unroll
    for (int h = 0; h < 16; ++h)
        #pragma unroll
        for (int si = 0; si < 4; ++si) acc[h][si] = 0.f;

    float4 xr[4];
    float tr[2];
    {
        #pragma unroll
        for (int k = 0; k < 4; ++k) {
            int i4 = k * 256 + tid, s = i4 >> 3, e4 = i4 & 7;
            xr[k] = *(const float4*)(xb + (size_t)s * E_ + 4 * e4);
        }
        #pragma unroll
        for (int k = 0; k < 2; ++k) {
            int idx = k * 256 + tid, hh = idx >> 5, e = idx & 31;
            tr[k] = tmat[hh * E_ + e];
        }
        #pragma unroll
        for (int k = 0; k < 4; ++k) {
            int i4 = k * 256 + tid, s = i4 >> 3, e4 = i4 & 7;
            *(float4*)&xs[s * 36 + 4 * e4] = xr[k];
        }
        #pragma unroll
        for (int k = 0; k < 2; ++k) {
            int idx = k * 256 + tid, hh = idx >> 5, e = idx & 31;
            ts[hh * 36 + e] = tr[k];
        }
    }
    for (int c = 0; c < 32; ++c) {
        __syncthreads();
        if (c + 1 < 32) {
            int ec = (c + 1) * 32;
            #pragma unroll
            for (int k = 0; k < 4; ++k) {
                int i4 = k * 256 + tid, s = i4 >> 3, e4 = i4 & 7;
                xr[k] = *(const float4*)(xb + (size_t)s * E_ + ec + 4 * e4);
            }
            #pragma unroll
            for (int k = 0; k < 2; ++k) {
                int idx = k * 256 + tid, hh = idx >> 5, e = idx & 31;
                tr[k] = tmat[hh * E_ + ec + e];
            }
        }
        const int bx = (c & 1) * 4608, bt = (c & 1) * 576;
        float4 xv[4];
        #pragma unroll
        for (int si = 0; si < 4; ++si)
            xv[si] = *(const float4*)&xs[bx + (sl + 32 * si) * 36 + 4 * qd];
        #pragma unroll
        for (int h = 0; h < 16; ++h) {
            float4 tf = *(const float4*)&ts[bt + h * 36 + 4 * qd];
            #pragma unroll
            for (int si = 0; si < 4; ++si)
                acc[h][si] += tf.x * xv[si].x + tf.y * xv[si].y + tf.z * xv[si].z + tf.w * xv[si].w;
        }
        if (c + 1 < 32) {
            const int nx = ((c + 1) & 1) * 4608, nt = ((c + 1) & 1) * 576;
            #pragma unroll
            for (int k = 0; k < 4; ++k) {
                int i4 = k * 256 + tid, s = i4 >> 3, e4 = i4 & 7;
                *(float4*)&xs[nx + s * 36 + 4 * e4] = xr[k];
            }
            #pragma unroll
            for (int k = 0; k < 2; ++k) {
                int idx = k * 256 + tid, hh = idx >> 5, e = idx & 31;
                ts[nt + hh * 36 + e] = tr[k];
            }
        }
    }
    __syncthreads();  // all phase-1 reads done; xs becomes reduce planes

    // cross-eh butterfly: sum the two 4-e halves within the wave
    #pragma unroll
    for (int h = 0; h < 16; ++h)
        #pragma unroll
        for (int si = 0; si < 4; ++si)
            acc[h][si] += __shfl_xor(acc[h][si], 32, 64);
    // plane write: lane-half eh stores heads 8eh..8eh+7 — CONSTANT acc indices,
    // predicated select; dynamic address only on the LDS side.
    {
        float* pl = xs + w * 2176;
        #pragma unroll
        for (int si = 0; si < 4; ++si) {
            int s = sl + 32 * si;
            #pragma unroll
            for (int hh = 0; hh < 8; ++hh) {
                float v = eh ? acc[8 + hh][si] : acc[hh][si];
                pl[s * 17 + 8 * eh + hh] = v;
            }
        }
    }
    __syncthreads();
    {
        const float* qbk = ws + OFF_QBK + b * H_;
        #pragma unroll
        for (int i = 0; i < 8; ++i) {
            int o = tid * 8 + i, s = o >> 4, h = o & 15;
            float v = xs[s * 17 + h] + xs[2176 + s * 17 + h] +
                      xs[4352 + s * 17 + h] + xs[6528 + s * 17 + h] + qbk[h];
            wl[s * 20 + h] = v;
        }
    }
    __syncthreads();

    // ================= softmax partials =================
    const int sh = tid & 15, seg = tid >> 4;
    {
        float m = -1e30f;
        #pragma unroll
        for (int i = 0; i < 8; ++i) m = fmaxf(m, wl[(seg * 8 + i) * 20 + sh]);
        red[seg * 16 + sh] = m;
    }
    __syncthreads();
    if (tid < 16) {
        float mm = -1e30f;
        for (int g = 0; g < 16; ++g) mm = fmaxf(mm, red[g * 16 + tid]);
        msh[tid] = mm;
    }
    __syncthreads();
    {
        float M = msh[sh];
        float ps = 0.f;
        #pragma unroll
        for (int i = 0; i < 8; ++i) {
            int idx = (seg * 8 + i) * 20 + sh;
            float v = __expf(wl[idx] - M);
            wl[idx] = v;
            ps += v;
        }
        __syncthreads();
        red[seg * 16 + sh] = ps;
    }
    __syncthreads();
    if (tid < 16) {
        float ss = 0.f;
        for (int g = 0; g < 16; ++g) ss += red[g * 16 + tid];
        ws[OFF_M + (b * NT_ + tile) * H_ + tid] = msh[tid];
        ws[OFF_L + (b * NT_ + tile) * H_ + tid] = ss;
    }

    // ================= phase 2: direct-global x, no LDS staging =================
    float4 a2[16];
    #pragma unroll
    for (int h = 0; h < 16; ++h) a2[h] = make_float4(0.f, 0.f, 0.f, 0.f);
    const float* xb2 = xb + w * 256 + 4 * lane;  // wave w owns e-slice [256w,256w+256)
    for (int s = 0; s < STILE; s += 4) {
        float4 xv[4];
        #pragma unroll
        for (int u = 0; u < 4; ++u)
            xv[u] = *(const float4*)(xb2 + (size_t)(s + u) * E_);
        #pragma unroll
        for (int u = 0; u < 4; ++u) {
            const float* wp = &wl[(s + u) * 20];
            float4 w0 = *(const float4*)(wp);
            float4 w1 = *(const float4*)(wp + 4);
            float4 w2 = *(const float4*)(wp + 8);
            float4 w3 = *(const float4*)(wp + 12);
            a2[0].x += w0.x * xv[u].x; a2[0].y += w0.x * xv[u].y; a2[0].z += w0.x * xv[u].z; a2[0].w += w0.x * xv[u].w;
            a2[1].x += w0.y * xv[u].x; a2[1].y += w0.y * xv[u].y; a2[1].z += w0.y * xv[u].z; a2[1].w += w0.y * xv[u].w;
            a2[2].x += w0.z * xv[u].x; a2[2].y += w0.z * xv[u].y; a2[2].z += w0.z * xv[u].z; a2[2].w += w0.z * xv[u].w;
            a2[3].x += w0.w * xv[u].x; a2[3].y += w0.w * xv[u].y; a2[3].z += w0.w * xv[u].z; a2[3].w += w0.w * xv[u].w;
            a2[4].x += w1.x * xv[u].x; a2[4].y += w1.x * xv[u].y; a2[4].z += w1.x * xv[u].z; a2[4].w += w1.x * xv[u].w;
            a2[5].x += w1.y * xv[u].x; a2[5].y += w1.y * xv[u].y; a2[5].z += w1.y * xv[u].z; a2[5].w += w1.y * xv[u].w;
            a2[6].x += w1.z * xv[u].x; a2[6].y += w1.z * xv[u].y; a2[6].z += w1.z * xv[u].z; a2[6].w += w1.z * xv[u].w;
            a2[7].x += w1.w * xv[u].x; a2[7].y += w1.w * xv[u].y; a2[7].z += w1.w * xv[u].z; a2[7].w += w1.w * xv[u].w;
            a2[8].x += w2.x * xv[u].x; a2[8].y += w2.x * xv[u].y; a2[8].z += w2.x * xv[u].z; a2[8].w += w2.x * xv[u].w;
            a2[9].x += w2.y * xv[u].x; a2[9].y += w2.y * xv[u].y; a2[9].z += w2.y * xv[u].z; a2[9].w += w2.y * xv[u].w;
            a2[10].x += w2.z * xv[u].x; a2[10].y += w2.z * xv[u].y; a2[10].z += w2.z * xv[u].z; a2[10].w += w2.z * xv[u].w;
            a2[11].x += w2.w * xv[u].x; a2[11].y += w2.w * xv[u].y; a2[11].z += w2.w * xv[u].z; a2[11].w += w2.w * xv[u].w;
            a2[12].x += w3.x * xv[u].x; a2[12].y += w3.x * xv[u].y; a2[12].z += w3.x * xv[u].z; a2[12].w += w3.x * xv[u].w;
            a2[13].x += w3.y * xv[u].x; a2[13].y += w3.y * xv[u].y; a2[13].z += w3.y * xv[u].z; a2[13].w += w3.y * xv[u].w;
            a2[14].x += w3.z * xv[u].x; a2[14].y += w3.z * xv[u].y; a2[14].z += w3.z * xv[u].z; a2[14].w += w3.z * xv[u].w;
            a2[15].x += w3.w * xv[u].x; a2[15].y += w3.w * xv[u].y; a2[15].z += w3.w * xv[u].z; a2[15].w += w3.w * xv[u].w;
        }
    }
    {
        unsigned short* up = (unsigned short*)(ws + OFF_UP) +
                             (size_t)((b * NT_ + tile) * H_) * E_ + w * 256 + 4 * lane;
        #pragma unroll
        for (int h = 0; h < 16; ++h) {
            uint2 p;
            p.x = bf16pair(a2[h].x, a2[h].y);
            p.y = bf16pair(a2[h].z, a2[h].w);
            *(uint2*)(up + (size_t)h * E_) = p;
        }
    }
}

// ---------------------------------------------------------------- combine partial tiles (bf16 UP)
__global__ __launch_bounds__(256) void k_combine(float* __restrict__ ws) {
    const int b = blockIdx.x, h = blockIdx.y, tid = threadIdx.x;
    float m[NT_], l[NT_], f[NT_];
    float M = -1e30f;
    #pragma unroll
    for (int tg = 0; tg < NT_; ++tg) {
        m[tg] = ws[OFF_M + (b * NT_ + tg) * H_ + h];
        l[tg] = ws[OFF_L + (b * NT_ + tg) * H_ + h];
        M = fmaxf(M, m[tg]);
    }
    float Ls = 0.f;
    #pragma unroll
    for (int tg = 0; tg < NT_; ++tg) {
        f[tg] = __expf(m[tg] - M);
        Ls += f[tg] * l[tg];
    }
    const float inv = 1.f / Ls;
    const unsigned short* up = (const unsigned short*)(ws + OFF_UP);
    float4 a = make_float4(0.f, 0.f, 0.f, 0.f);
    #pragma unroll
    for (int tg = 0; tg < NT_; ++tg) {
        uint2 p = *(const uint2*)(up + (size_t)((b * NT_ + tg) * H_ + h) * E_ + 4 * tid);
        float v0 = __uint_as_float((p.x & 0xFFFFu) << 16);
        float v1 = __uint_as_float(p.x & 0xFFFF0000u);
        float v2 = __uint_as_float((p.y & 0xFFFFu) << 16);
        float v3 = __uint_as_float(p.y & 0xFFFF0000u);
        a.x += f[tg] * v0; a.y += f[tg] * v1; a.z += f[tg] * v2; a.w += f[tg] * v3;
    }
    a.x *= inv; a.y *= inv; a.z *= inv; a.w *= inv;
    *(float4*)(ws + OFF_U + (size_t)(b * H_ + h) * E_ + 4 * tid) = a;
}

// ---------------------------------------------------------------- LayerNorm -> out
__global__ __launch_bounds__(256) void k_ln(const float* __restrict__ ws,
                                            const float* __restrict__ g,
                                            const float* __restrict__ be,
                                            float* __restrict__ out) {
    const int b = blockIdx.x, tid = threadIdx.x;
    const float* y = ws + OFF_Y + (size_t)b * E_;
    float4 v = *(const float4*)(y + 4 * tid);
    float s = v.x + v.y + v.z + v.w;
    float s2 = v.x * v.x + v.y * v.y + v.z * v.z + v.w * v.w;
    for (int o = 32; o; o >>= 1) {
        s += __shfl_down(s, o, 64);
        s2 += __shfl_down(s2, o, 64);
    }
    __shared__ float rs[4], rs2[4];
    int ww = tid >> 6;
    if ((tid & 63) == 0) { rs[ww] = s; rs2[ww] = s2; }
    __syncthreads();
    float S = rs[0] + rs[1] + rs[2] + rs[3];
    float S2 = rs2[0] + rs2[1] + rs2[2] + rs2[3];
    float mean = S * (1.f / 1024.f);
    float var = S2 * (1.f / 1024.f) - mean * mean;
    float r = rsqrtf(var + 1e-5f);
    float4 gv = *(const float4*)(g + 4 * tid);
    float4 bb2 = *(const float4*)(be + 4 * tid);
    float4 o;
    o.x = (v.x - mean) * r * gv.x + bb2.x;
    o.y = (v.y - mean) * r * gv.y + bb2.y;
    o.z = (v.z - mean) * r * gv.z + bb2.z;
    o.w = (v.w - mean) * r * gv.w + bb2.w;
    *(float4*)(out + (size_t)b * E_ + 4 * tid) = o;
}

extern "C" void kernel_launch(void* const* d_in, const int* in_sizes, int n_in,
                              void* d_out, int out_size, void* d_ws, size_t ws_size,
                              hipStream_t stream) {
    const float* x  = (const float*)d_in[0];
    const float* Wq = (const float*)d_in[1];
    const float* bq = (const float*)d_in[2];
    const float* Wk = (const float*)d_in[3];
    const float* bk = (const float*)d_in[4];
    const float* Wv = (const float*)d_in[5];
    const float* bv = (const float*)d_in[6];
    const float* Wo = (const float*)d_in[7];
    const float* bo = (const float*)d_in[8];
    const float* g  = (const float*)d_in[9];
    const float* be = (const float*)d_in[10];
    float* ws = (float*)d_ws;
    float* out = (float*)d_out;

    k_gemm32<<<512, 256, 0, stream>>>(x, (long long)L_ * E_, 0, Wq, bq, nullptr, 0, ws + OFF_Q);
    k_tproj<<<dim3(16, 16), 256, 0, stream>>>(Wk, bk, ws);
    k_attn_core<<<dim3(NT_, B_), 256, 0, stream>>>(x, ws);
    k_combine<<<dim3(B_, H_), 256, 0, stream>>>(ws);
    k_gemm32<<<512, 256, 0, stream>>>(ws + OFF_U, (long long)H_ * E_, 1, Wv, bv, nullptr, 0, ws + OFF_ATTN);
    k_gemm32<<<512, 256, 0, stream>>>(ws + OFF_ATTN, (long long)E_, 0, Wo, bo, x, (long long)L_ * E_, ws + OFF_Y);
    k_ln<<<B_, 256, 0, stream>>>(ws, g, be, out);
}